// Round 8
// baseline (8292.669 us; speedup 1.0000x reference)
//
#include <hip/hip_runtime.h>

#define B_   256
#define T_   168
#define IN_  64
#define H_   512
#define G_   2048
#define HOR_ 24
#define NHH  (B_ * H_)          // elements per h buffer slot (131072)
#define CPAD 32                 // counter padding in u32 (128 B lines)
#define EPOCHS (T_ + HOR_ + 1)  // 193 h-epochs per layer

typedef unsigned short u16;
typedef __bf16 bf16x8 __attribute__((ext_vector_type(8)));
typedef float  f32x4  __attribute__((ext_vector_type(4)));

__device__ __forceinline__ u16 f2bf(float f) {
  unsigned u = __float_as_uint(f);
  u += 0x7fffu + ((u >> 16) & 1u);   // round-to-nearest-even
  return (u16)(u >> 16);
}
__device__ __forceinline__ float bf2f(u16 h) {
  return __uint_as_float(((unsigned)h) << 16);
}

// coherent (write-through to L3) u16 store — cross-XCD visible without fences
__device__ __forceinline__ void coh_store_u16(u16* p, unsigned v) {
  asm volatile("global_store_short %0, %1, off sc0 sc1" :: "v"(p), "v"(v) : "memory");
}
__device__ __forceinline__ void vmdrain() {
  asm volatile("s_waitcnt vmcnt(0)" ::: "memory");
}

// ---------------- split fp32 -> bf16 hi + bf16 lo ----------------
__global__ __launch_bounds__(256) void split_kernel(const float* __restrict__ src,
                                                    u16* __restrict__ hi,
                                                    u16* __restrict__ lo, int n4) {
  int i = blockIdx.x * 256 + threadIdx.x;
  if (i >= n4) return;
  float4 v = ((const float4*)src)[i];
  ushort4 h, l;
  h.x = f2bf(v.x); l.x = f2bf(v.x - bf2f(h.x));
  h.y = f2bf(v.y); l.y = f2bf(v.y - bf2f(h.y));
  h.z = f2bf(v.z); l.z = f2bf(v.z - bf2f(h.z));
  h.w = f2bf(v.w); l.w = f2bf(v.w - bf2f(h.w));
  ((ushort4*)hi)[i] = h;
  ((ushort4*)lo)[i] = l;
}

// ---------------- What = outer(dW0, fcW), split to hi/lo ----------------
__global__ __launch_bounds__(256) void outer_kernel(const float* __restrict__ dW0,
                                                    const float* __restrict__ fcW,
                                                    u16* __restrict__ Wh, u16* __restrict__ Wl) {
  int i = blockIdx.x * 256 + threadIdx.x;   // over 2048*512
  int c = i >> 9, k = i & 511;
  float w = dW0[c] * fcW[k];
  u16 h = f2bf(w);
  Wh[i] = h; Wl[i] = f2bf(w - bf2f(h));
}

// b0p[c] = db0[c] + dW0[c]*fcb
__global__ __launch_bounds__(256) void bias_kernel(const float* __restrict__ db0,
                                                   const float* __restrict__ dW0,
                                                   const float* __restrict__ fcb,
                                                   float* __restrict__ b0p) {
  int i = blockIdx.x * 256 + threadIdx.x;
  if (i < G_) b0p[i] = db0[i] + dW0[i] * fcb[0];
}

// ---------------- one LSTM layer-step job (GEMM + pointwise) ----------------
struct Job {
  const u16 *A1h, *A1l, *W1h, *W1l;
  const u16 *A2h, *A2l, *W2h, *W2l;
  const float* bias;
  float* c; u16 *Hh, *Hl;
  int a1Stride, K1;
};

// 512-thread block: 8 waves = (mb: 16-row half) x (sp: strip-pair) x (kh: K-half).
// K-halves reduced through LDS; (sp0,kh0) waves do the pointwise epilogue.
__device__ __forceinline__ void run_job(const Job& J, int bx) {
  const int hc   = bx & 31;          // hcol tile * 16 (bid%8 = hc%8 -> stable XCD home)
  const int mt   = bx >> 5;          // m tile * 32
  const int lane = threadIdx.x & 63;
  const int wave = threadIdx.x >> 6; // 0..7
  const int mb   = wave & 1;
  const int sp   = (wave >> 1) & 1;  // 0 -> gates (i,f), 1 -> (g,o)
  const int kh   = wave >> 2;        // K-half
  const int l16  = lane & 15;
  const int lk   = lane >> 4;
  const int arow = mt * 32 + mb * 16 + l16;
  const int hcb  = hc * 16;
  const int s0   = sp * 2;

  f32x4 acc0 = {0.f, 0.f, 0.f, 0.f};
  f32x4 acc1 = {0.f, 0.f, 0.f, 0.f};

  #pragma unroll 1
  for (int seg = 0; seg < 2; ++seg) {
    const u16 *Ah, *Al, *Wh, *Wl; int K, astr;
    if (seg == 0) {
      K = J.K1; if (K == 0) continue;
      Ah = J.A1h; Al = J.A1l; Wh = J.W1h; Wl = J.W1l; astr = J.a1Stride;
    } else {
      Ah = J.A2h; Al = J.A2l; Wh = J.W2h; Wl = J.W2l; K = 512; astr = 512;
    }
    int kbeg, kend;
    if (K >= 128) { int half = K >> 1; kbeg = kh * half; kend = kbeg + half; }
    else          { kbeg = 0; kend = (kh == 0) ? K : 0; }
    const u16* aph = Ah + (size_t)arow * astr + lk * 8;
    const u16* apl = Al + (size_t)arow * astr + lk * 8;
    const size_t w0 = (size_t)(s0 * 512 + hcb + l16) * K + lk * 8;
    const size_t w1 = (size_t)((s0 + 1) * 512 + hcb + l16) * K + lk * 8;
    const u16 *bh0 = Wh + w0, *bl0 = Wl + w0, *bh1 = Wh + w1, *bl1 = Wl + w1;
    #pragma unroll 1
    for (int k = kbeg; k < kend; k += 64) {   // unroll-2: 12 loads in flight
      bf16x8 ahA  = *(const bf16x8*)(aph + k);
      bf16x8 alA  = *(const bf16x8*)(apl + k);
      bf16x8 p0hA = *(const bf16x8*)(bh0 + k);
      bf16x8 p0lA = *(const bf16x8*)(bl0 + k);
      bf16x8 p1hA = *(const bf16x8*)(bh1 + k);
      bf16x8 p1lA = *(const bf16x8*)(bl1 + k);
      bf16x8 ahB  = *(const bf16x8*)(aph + k + 32);
      bf16x8 alB  = *(const bf16x8*)(apl + k + 32);
      bf16x8 p0hB = *(const bf16x8*)(bh0 + k + 32);
      bf16x8 p0lB = *(const bf16x8*)(bl0 + k + 32);
      bf16x8 p1hB = *(const bf16x8*)(bh1 + k + 32);
      bf16x8 p1lB = *(const bf16x8*)(bl1 + k + 32);
      acc0 = __builtin_amdgcn_mfma_f32_16x16x32_bf16(ahA, p0hA, acc0, 0, 0, 0);
      acc1 = __builtin_amdgcn_mfma_f32_16x16x32_bf16(ahA, p1hA, acc1, 0, 0, 0);
      acc0 = __builtin_amdgcn_mfma_f32_16x16x32_bf16(ahA, p0lA, acc0, 0, 0, 0);
      acc1 = __builtin_amdgcn_mfma_f32_16x16x32_bf16(ahA, p1lA, acc1, 0, 0, 0);
      acc0 = __builtin_amdgcn_mfma_f32_16x16x32_bf16(alA, p0hA, acc0, 0, 0, 0);
      acc1 = __builtin_amdgcn_mfma_f32_16x16x32_bf16(alA, p1hA, acc1, 0, 0, 0);
      acc0 = __builtin_amdgcn_mfma_f32_16x16x32_bf16(ahB, p0hB, acc0, 0, 0, 0);
      acc1 = __builtin_amdgcn_mfma_f32_16x16x32_bf16(ahB, p1hB, acc1, 0, 0, 0);
      acc0 = __builtin_amdgcn_mfma_f32_16x16x32_bf16(ahB, p0lB, acc0, 0, 0, 0);
      acc1 = __builtin_amdgcn_mfma_f32_16x16x32_bf16(ahB, p1lB, acc1, 0, 0, 0);
      acc0 = __builtin_amdgcn_mfma_f32_16x16x32_bf16(alB, p0hB, acc0, 0, 0, 0);
      acc1 = __builtin_amdgcn_mfma_f32_16x16x32_bf16(alB, p1hB, acc1, 0, 0, 0);
    }
  }

  // K-half + strip exchange. Slots: (sp0,kh1)->0,1  (sp1,kh0)->2,3  (sp1,kh1)->4,5
  __shared__ float xch[6][2][16][17];
  if (sp | kh) {
    const int ws = (sp * 2 + kh) * 2 - 2;
    #pragma unroll
    for (int r = 0; r < 4; ++r) {
      xch[ws][mb][lk * 4 + r][l16]     = acc0[r];
      xch[ws + 1][mb][lk * 4 + r][l16] = acc1[r];
    }
  }
  __syncthreads();
  if (sp == 0 && kh == 0) {
    const int hcol = hcb + l16;
    const float bi = J.bias[hcol];
    const float bf = J.bias[512 + hcol];
    const float bg = J.bias[1024 + hcol];
    const float bo = J.bias[1536 + hcol];
    #pragma unroll
    for (int r = 0; r < 4; ++r) {
      const int rr = lk * 4 + r;
      const int row = mt * 32 + mb * 16 + rr;
      const size_t idx = (size_t)row * 512 + hcol;
      float gi = acc0[r] + xch[0][mb][rr][l16] + bi;
      float gf = acc1[r] + xch[1][mb][rr][l16] + bf;
      float gg = xch[2][mb][rr][l16] + xch[4][mb][rr][l16] + bg;
      float go = xch[3][mb][rr][l16] + xch[5][mb][rr][l16] + bo;
      float si = 1.f / (1.f + expf(-gi));
      float sf = 1.f / (1.f + expf(-gf));
      float so = 1.f / (1.f + expf(-go));
      float cn = sf * J.c[idx] + si * tanhf(gg);
      float hn = so * tanhf(cn);
      J.c[idx] = cn;                      // block-private: normal store
      u16 hh = f2bf(hn);
      coh_store_u16(J.Hh + idx, (unsigned)hh);
      coh_store_u16(J.Hl + idx, (unsigned)(u16)f2bf(hn - bf2f(hh)));
    }
    vmdrain();   // h at coherence point before the counter add
  }
}

// fc for 32 rows per block (8 blocks cover B=256); 512 threads
__device__ __forceinline__ void fc_block(const u16* Hh, const u16* Hl,
                                         const float* fcW, const float* fcb,
                                         float* dout, int step, int b2) {
  int tid = threadIdx.x;
  int r = b2 * 32 + (tid >> 4);
  int cc = tid & 15;
  float s = 0.f;
  int k0 = cc * 32;
  for (int k = k0; k < k0 + 32; ++k) {
    float h = bf2f(Hh[(size_t)r * 512 + k]) + bf2f(Hl[(size_t)r * 512 + k]);
    s += h * fcW[k];
  }
  for (int off = 8; off; off >>= 1) s += __shfl_down(s, off, 16);
  if (cc == 0) dout[(size_t)r * HOR_ + step] = s + fcb[0];
}

// ---------------- dataflow sync primitives (no fences, no barriers) ----------------
struct WaitC { unsigned* p; unsigned t; };

__device__ __forceinline__ bool block_wait(const WaitC* w, int n) {
  __shared__ int okk;
  __syncthreads();                 // also protects xch reuse across phases
  if (threadIdx.x == 0) {
    int ok = 1;
    for (int i = 0; i < n && ok; ++i) {
      long spins = 0;
      while (__hip_atomic_load(w[i].p, __ATOMIC_RELAXED, __HIP_MEMORY_SCOPE_AGENT) < w[i].t) {
        __builtin_amdgcn_s_sleep(1);
        if (++spins > 3000000) { ok = 0; break; }   // bounded: bail, don't hang
      }
    }
    okk = ok;
  }
  __syncthreads();
  asm volatile("" ::: "memory");   // keep data loads after the spin
  return okk != 0;
}

__device__ __forceinline__ void post(unsigned* cnt) {
  __syncthreads();                 // all waves' coherent stores drained (vmdrain per wave)
  if (threadIdx.x == 0)
    __hip_atomic_fetch_add(cnt, 1u, __ATOMIC_RELAXED, __HIP_MEMORY_SCOPE_AGENT);
}

// ---------------- persistent dataflow mega kernel ----------------
struct MegaParams {
  const u16 *xh, *xl;
  const u16 *eW0h, *eW0l, *eU0h, *eU0l, *eW1h, *eW1l, *eU1h, *eU1l;
  const u16 *dU0h, *dU0l, *dW1h, *dW1l, *dU1h, *dU1l, *Whh, *Whl;
  const float *eb0, *eb1, *db0, *db1, *b0p, *fcW, *fcb;
  u16 *h0h, *h0l, *h1h, *h1l;     // slot arrays: R slots of NHH u16 each
  float *c0, *c1, *dout;
  unsigned *cnt0, *cnt1;          // per-mt monotone production counters (x32 pad)
  int R;
};

__global__ __launch_bounds__(512, 4) void mega_kernel(MegaParams P) {
  const int bid = blockIdx.x;
  const int R = P.R;

  if (bid < 256) {
    // ---------------- L0 chain ----------------
    const int bx = bid, mt = bx >> 5;
    unsigned* myc = P.cnt0 + mt * CPAD;
    unsigned* oth = P.cnt1 + mt * CPAD;
    // encoder L0: phase t produces h0 epoch t+1
    for (int t = 0; t < T_; ++t) {
      WaitC w[2]; int n = 0;
      if (t >= 1)       w[n++] = {myc, 32u * t};              // A2 = h0 epoch t
      if (t + 1 >= R)   w[n++] = {oth, 32u * (t + 1 - R)};    // ring WAR vs L1 readers
      if (!block_wait(w, n)) return;
      Job J;
      J.A1h = P.xh + (size_t)t * IN_; J.A1l = P.xl + (size_t)t * IN_;
      J.a1Stride = T_ * IN_; J.K1 = IN_;
      J.W1h = P.eW0h; J.W1l = P.eW0l;
      J.A2h = P.h0h + (size_t)(t % R) * NHH; J.A2l = P.h0l + (size_t)(t % R) * NHH;
      J.W2h = P.eU0h; J.W2l = P.eU0l; J.bias = P.eb0; J.c = P.c0;
      J.Hh = P.h0h + (size_t)((t + 1) % R) * NHH; J.Hl = P.h0l + (size_t)((t + 1) % R) * NHH;
      run_job(J, bx);
      post(myc);
    }
    // decoder L0 (fc folded via What): step s produces h0 epoch T+s+1
    for (int s = 0; s < HOR_; ++s) {
      const int e = T_ + s + 1;
      WaitC w[3]; int n = 0;
      w[n++] = {myc, 32u * (T_ + s)};                          // A2 = h0 epoch T+s
      if (s >= 1)              w[n++] = {oth, 32u * (T_ + s)}; // A1 = h1 epoch T+s
      else if (e >= R)         w[n++] = {oth, 32u * (e - R)};  // ring WAR (s=0 only)
      if (!block_wait(w, n)) return;
      Job J;
      J.A1h = P.h1h + (size_t)((T_ + s) % R) * NHH; J.A1l = P.h1l + (size_t)((T_ + s) % R) * NHH;
      J.a1Stride = 512; J.K1 = (s == 0 ? 0 : 512);
      J.W1h = P.Whh; J.W1l = P.Whl;
      J.A2h = P.h0h + (size_t)((T_ + s) % R) * NHH; J.A2l = P.h0l + (size_t)((T_ + s) % R) * NHH;
      J.W2h = P.dU0h; J.W2l = P.dU0l;
      J.bias = (s == 0 ? P.db0 : P.b0p); J.c = P.c0;
      J.Hh = P.h0h + (size_t)(e % R) * NHH; J.Hl = P.h0l + (size_t)(e % R) * NHH;
      run_job(J, bx);
      post(myc);
    }
  } else {
    // ---------------- L1 chain (+ fc piggyback on bx<8) ----------------
    const int bx = bid - 256, mt = bx >> 5;
    unsigned* myc = P.cnt1 + mt * CPAD;
    unsigned* oth = P.cnt0 + mt * CPAD;
    // encoder L1: phase t (1..T) produces h1 epoch t
    for (int t = 1; t <= T_; ++t) {
      WaitC w[2]; int n = 0;
      w[n++] = {oth, 32u * t};                                 // A1 = h0 epoch t
      if (t >= 2) w[n++] = {myc, 32u * (t - 1)};               // A2 = h1 epoch t-1
      if (!block_wait(w, n)) return;
      Job J;
      J.A1h = P.h0h + (size_t)(t % R) * NHH; J.A1l = P.h0l + (size_t)(t % R) * NHH;
      J.a1Stride = 512; J.K1 = 512;
      J.W1h = P.eW1h; J.W1l = P.eW1l;
      J.A2h = P.h1h + (size_t)((t - 1) % R) * NHH; J.A2l = P.h1l + (size_t)((t - 1) % R) * NHH;
      J.W2h = P.eU1h; J.W2l = P.eU1l; J.bias = P.eb1; J.c = P.c1;
      J.Hh = P.h1h + (size_t)(t % R) * NHH; J.Hl = P.h1l + (size_t)(t % R) * NHH;
      run_job(J, bx);
      post(myc);
    }
    // decoder L1: step s produces h1 epoch T+s+1; fc(s-1) first on bx<8
    for (int s = 0; s < HOR_; ++s) {
      if (bx < 8 && s >= 1) {
        WaitC w = {P.cnt1 + bx * CPAD, 32u * (T_ + s)};        // h1 epoch T+s rows of mt-tile bx
        if (!block_wait(&w, 1)) return;
        fc_block(P.h1h + (size_t)((T_ + s) % R) * NHH, P.h1l + (size_t)((T_ + s) % R) * NHH,
                 P.fcW, P.fcb, P.dout, s - 1, bx);
      }
      const int e = T_ + s + 1;
      WaitC w[3]; int n = 0;
      w[n++] = {oth, 32u * (T_ + s + 1)};                      // A1 = h0 epoch T+s+1
      w[n++] = {myc, 32u * (T_ + s)};                          // A2 = h1 epoch T+s
      if (e >= R && e - R > T_) w[n++] = {P.cnt1, 32u * (e - R + 1)};  // ring WAR vs fc readers
      if (!block_wait(w, n)) return;
      Job J;
      J.A1h = P.h0h + (size_t)(e % R) * NHH; J.A1l = P.h0l + (size_t)(e % R) * NHH;
      J.a1Stride = 512; J.K1 = 512;
      J.W1h = P.dW1h; J.W1l = P.dW1l;
      J.A2h = P.h1h + (size_t)((T_ + s) % R) * NHH; J.A2l = P.h1l + (size_t)((T_ + s) % R) * NHH;
      J.W2h = P.dU1h; J.W2l = P.dU1l; J.bias = P.db1; J.c = P.c1;
      J.Hh = P.h1h + (size_t)(e % R) * NHH; J.Hl = P.h1l + (size_t)(e % R) * NHH;
      run_job(J, bx);
      post(myc);
    }
    if (bx < 8) {
      WaitC w = {P.cnt1 + bx * CPAD, 32u * (T_ + HOR_)};
      if (!block_wait(&w, 1)) return;
      fc_block(P.h1h + (size_t)((T_ + HOR_) % R) * NHH, P.h1l + (size_t)((T_ + HOR_) % R) * NHH,
               P.fcW, P.fcb, P.dout, HOR_ - 1, bx);
    }
  }
}

// ---------------- host ----------------
extern "C" void kernel_launch(void* const* d_in, const int* in_sizes, int n_in,
                              void* d_out, int out_size, void* d_ws, size_t ws_size,
                              hipStream_t stream) {
  const float* x   = (const float*)d_in[0];
  const float* eW0 = (const float*)d_in[2];
  const float* eU0 = (const float*)d_in[3];
  const float* eb0 = (const float*)d_in[4];
  const float* eW1 = (const float*)d_in[5];
  const float* eU1 = (const float*)d_in[6];
  const float* eb1 = (const float*)d_in[7];
  const float* dW0 = (const float*)d_in[8];
  const float* dU0 = (const float*)d_in[9];
  const float* db0 = (const float*)d_in[10];
  const float* dW1 = (const float*)d_in[11];
  const float* dU1 = (const float*)d_in[12];
  const float* db1 = (const float*)d_in[13];
  const float* fcW = (const float*)d_in[14];
  const float* fcb = (const float*)d_in[15];
  float* dout = (float*)d_out;

  char* base = (char*)d_ws;
  size_t off = 0;
  auto alloc = [&](size_t bytes) -> char* {
    char* p = base + off;
    off = (off + bytes + 255) & ~(size_t)255;
    return p;
  };

  const size_t nx  = (size_t)B_ * T_ * IN_;
  const size_t nW0 = (size_t)G_ * IN_;
  const size_t nWH = (size_t)G_ * H_;
  u16* xhi = (u16*)alloc(nx * 2);
  u16* xlo = (u16*)alloc(nx * 2);
  u16 *eW0h = (u16*)alloc(nW0 * 2), *eW0l = (u16*)alloc(nW0 * 2);
  u16 *eU0h = (u16*)alloc(nWH * 2), *eU0l = (u16*)alloc(nWH * 2);
  u16 *eW1h = (u16*)alloc(nWH * 2), *eW1l = (u16*)alloc(nWH * 2);
  u16 *eU1h = (u16*)alloc(nWH * 2), *eU1l = (u16*)alloc(nWH * 2);
  u16 *dU0h = (u16*)alloc(nWH * 2), *dU0l = (u16*)alloc(nWH * 2);
  u16 *dW1h = (u16*)alloc(nWH * 2), *dW1l = (u16*)alloc(nWH * 2);
  u16 *dU1h = (u16*)alloc(nWH * 2), *dU1l = (u16*)alloc(nWH * 2);
  u16 *Whh  = (u16*)alloc(nWH * 2), *Whl  = (u16*)alloc(nWH * 2);
  float* b0p = (float*)alloc(G_ * 4);

  // zero-initialized region: c0, c1, counters
  char* zbase = base + off;
  float* c0 = (float*)alloc((size_t)NHH * 4);
  float* c1 = (float*)alloc((size_t)NHH * 4);
  unsigned* cnt0 = (unsigned*)alloc(8 * CPAD * 4);
  unsigned* cnt1 = (unsigned*)alloc(8 * CPAD * 4);
  size_t zbytes = (size_t)((base + off) - zbase);

  // epoch-strided h slot arrays: R slots each (full stride if ws allows)
  size_t perR = (size_t)NHH * 2 * 4;          // 4 arrays x NHH u16 = 1 MiB per slot
  size_t availR = (ws_size > off + perR * 2) ? (ws_size - off) / perR : 2;
  int R = (int)(availR < (size_t)EPOCHS ? availR : (size_t)EPOCHS);
  if (R < 2) R = 2;
  u16* h0h = (u16*)alloc((size_t)R * NHH * 2);
  u16* h0l = (u16*)alloc((size_t)R * NHH * 2);
  u16* h1h = (u16*)alloc((size_t)R * NHH * 2);
  u16* h1l = (u16*)alloc((size_t)R * NHH * 2);
  (void)in_sizes; (void)n_in; (void)out_size;

  hipMemsetAsync(zbase, 0, zbytes, stream);
  hipMemsetAsync(h0h, 0, (size_t)NHH * 2, stream);   // slot 0 = h0 epoch 0 = zeros
  hipMemsetAsync(h0l, 0, (size_t)NHH * 2, stream);
  hipMemsetAsync(h1h, 0, (size_t)NHH * 2, stream);
  hipMemsetAsync(h1l, 0, (size_t)NHH * 2, stream);

  auto split = [&](const float* s, u16* h, u16* l, size_t n) {
    int n4 = (int)(n / 4);
    split_kernel<<<dim3((n4 + 255) / 256), dim3(256), 0, stream>>>(s, h, l, n4);
  };
  split(x, xhi, xlo, nx);
  split(eW0, eW0h, eW0l, nW0);
  split(eU0, eU0h, eU0l, nWH);
  split(eW1, eW1h, eW1l, nWH);
  split(eU1, eU1h, eU1l, nWH);
  split(dU0, dU0h, dU0l, nWH);
  split(dW1, dW1h, dW1l, nWH);
  split(dU1, dU1h, dU1l, nWH);
  outer_kernel<<<dim3((int)(nWH / 256)), dim3(256), 0, stream>>>(dW0, fcW, Whh, Whl);
  bias_kernel<<<dim3((G_ + 255) / 256), dim3(256), 0, stream>>>(db0, dW0, fcb, b0p);

  MegaParams P;
  P.xh = xhi; P.xl = xlo;
  P.eW0h = eW0h; P.eW0l = eW0l; P.eU0h = eU0h; P.eU0l = eU0l;
  P.eW1h = eW1h; P.eW1l = eW1l; P.eU1h = eU1h; P.eU1l = eU1l;
  P.dU0h = dU0h; P.dU0l = dU0l; P.dW1h = dW1h; P.dW1l = dW1l;
  P.dU1h = dU1h; P.dU1l = dU1l; P.Whh = Whh; P.Whl = Whl;
  P.eb0 = eb0; P.eb1 = eb1; P.db0 = db0; P.db1 = db1; P.b0p = b0p;
  P.fcW = fcW; P.fcb = fcb;
  P.h0h = h0h; P.h0l = h0l; P.h1h = h1h; P.h1l = h1l;
  P.c0 = c0; P.c1 = c1; P.dout = dout;
  P.cnt0 = cnt0; P.cnt1 = cnt1; P.R = R;

  mega_kernel<<<dim3(512), dim3(512), 0, stream>>>(P);
}

// Round 9
// 8243.542 us; speedup vs baseline: 1.0060x; 1.0060x over previous
//
#include <hip/hip_runtime.h>

#define B_   256
#define T_   168
#define IN_  64
#define H_   512
#define G_   2048
#define HOR_ 24
#define NHH  (B_ * H_)          // elements per h buffer slot (131072)
#define CPAD 32                 // counter padding in u32 (128 B lines)
#define EPOCHS (T_ + HOR_ + 1)  // 193 h-epochs per layer

typedef unsigned short u16;
typedef __bf16 bf16x8 __attribute__((ext_vector_type(8)));
typedef float  f32x4  __attribute__((ext_vector_type(4)));

__device__ __forceinline__ u16 f2bf(float f) {
  unsigned u = __float_as_uint(f);
  u += 0x7fffu + ((u >> 16) & 1u);   // round-to-nearest-even
  return (u16)(u >> 16);
}
__device__ __forceinline__ float bf2f(u16 h) {
  return __uint_as_float(((unsigned)h) << 16);
}

// coherent (write-through to L3) u16 store — cross-XCD visible without fences
__device__ __forceinline__ void coh_store_u16(u16* p, unsigned v) {
  asm volatile("global_store_short %0, %1, off sc0 sc1" :: "v"(p), "v"(v) : "memory");
}
__device__ __forceinline__ void vmdrain() {
  asm volatile("s_waitcnt vmcnt(0)" ::: "memory");
}
// L2-BYPASSING load (system-scope read from the L3 coherence point).
// A plain cached load can spin forever on a stale clean L2 line — per-XCD L2s
// are NOT invalidated by another XCD's atomics (round-8 lesson: ~35us/step).
__device__ __forceinline__ unsigned coh_load_u32(const unsigned* p) {
  unsigned v;
  asm volatile("global_load_dword %0, %1, off sc0 sc1\n\t"
               "s_waitcnt vmcnt(0)"
               : "=v"(v) : "v"(p) : "memory");
  return v;
}

// ---------------- split fp32 -> bf16 hi + bf16 lo ----------------
__global__ __launch_bounds__(256) void split_kernel(const float* __restrict__ src,
                                                    u16* __restrict__ hi,
                                                    u16* __restrict__ lo, int n4) {
  int i = blockIdx.x * 256 + threadIdx.x;
  if (i >= n4) return;
  float4 v = ((const float4*)src)[i];
  ushort4 h, l;
  h.x = f2bf(v.x); l.x = f2bf(v.x - bf2f(h.x));
  h.y = f2bf(v.y); l.y = f2bf(v.y - bf2f(h.y));
  h.z = f2bf(v.z); l.z = f2bf(v.z - bf2f(h.z));
  h.w = f2bf(v.w); l.w = f2bf(v.w - bf2f(h.w));
  ((ushort4*)hi)[i] = h;
  ((ushort4*)lo)[i] = l;
}

// ---------------- What = outer(dW0, fcW), split to hi/lo ----------------
__global__ __launch_bounds__(256) void outer_kernel(const float* __restrict__ dW0,
                                                    const float* __restrict__ fcW,
                                                    u16* __restrict__ Wh, u16* __restrict__ Wl) {
  int i = blockIdx.x * 256 + threadIdx.x;   // over 2048*512
  int c = i >> 9, k = i & 511;
  float w = dW0[c] * fcW[k];
  u16 h = f2bf(w);
  Wh[i] = h; Wl[i] = f2bf(w - bf2f(h));
}

// b0p[c] = db0[c] + dW0[c]*fcb
__global__ __launch_bounds__(256) void bias_kernel(const float* __restrict__ db0,
                                                   const float* __restrict__ dW0,
                                                   const float* __restrict__ fcb,
                                                   float* __restrict__ b0p) {
  int i = blockIdx.x * 256 + threadIdx.x;
  if (i < G_) b0p[i] = db0[i] + dW0[i] * fcb[0];
}

// ---------------- one LSTM layer-step job (GEMM + pointwise) ----------------
struct Job {
  const u16 *A1h, *A1l, *W1h, *W1l;
  const u16 *A2h, *A2l, *W2h, *W2l;
  const float* bias;
  float* c; u16 *Hh, *Hl;
  int a1Stride, K1;
};

// 512-thread block: 8 waves = (mb: 16-row half) x (sp: strip-pair) x (kh: K-half).
// K-halves reduced through LDS; (sp0,kh0) waves do the pointwise epilogue.
__device__ __forceinline__ void run_job(const Job& J, int bx) {
  const int hc   = bx & 31;          // hcol tile * 16 (bid%8 = hc%8 -> stable XCD home)
  const int mt   = bx >> 5;          // m tile * 32
  const int lane = threadIdx.x & 63;
  const int wave = threadIdx.x >> 6; // 0..7
  const int mb   = wave & 1;
  const int sp   = (wave >> 1) & 1;  // 0 -> gates (i,f), 1 -> (g,o)
  const int kh   = wave >> 2;        // K-half
  const int l16  = lane & 15;
  const int lk   = lane >> 4;
  const int arow = mt * 32 + mb * 16 + l16;
  const int hcb  = hc * 16;
  const int s0   = sp * 2;

  f32x4 acc0 = {0.f, 0.f, 0.f, 0.f};
  f32x4 acc1 = {0.f, 0.f, 0.f, 0.f};

  #pragma unroll 1
  for (int seg = 0; seg < 2; ++seg) {
    const u16 *Ah, *Al, *Wh, *Wl; int K, astr;
    if (seg == 0) {
      K = J.K1; if (K == 0) continue;
      Ah = J.A1h; Al = J.A1l; Wh = J.W1h; Wl = J.W1l; astr = J.a1Stride;
    } else {
      Ah = J.A2h; Al = J.A2l; Wh = J.W2h; Wl = J.W2l; K = 512; astr = 512;
    }
    int kbeg, kend;
    if (K >= 128) { int half = K >> 1; kbeg = kh * half; kend = kbeg + half; }
    else          { kbeg = 0; kend = (kh == 0) ? K : 0; }
    const u16* aph = Ah + (size_t)arow * astr + lk * 8;
    const u16* apl = Al + (size_t)arow * astr + lk * 8;
    const size_t w0 = (size_t)(s0 * 512 + hcb + l16) * K + lk * 8;
    const size_t w1 = (size_t)((s0 + 1) * 512 + hcb + l16) * K + lk * 8;
    const u16 *bh0 = Wh + w0, *bl0 = Wl + w0, *bh1 = Wh + w1, *bl1 = Wl + w1;
    #pragma unroll 1
    for (int k = kbeg; k < kend; k += 64) {   // unroll-2: 12 loads in flight
      bf16x8 ahA  = *(const bf16x8*)(aph + k);
      bf16x8 alA  = *(const bf16x8*)(apl + k);
      bf16x8 p0hA = *(const bf16x8*)(bh0 + k);
      bf16x8 p0lA = *(const bf16x8*)(bl0 + k);
      bf16x8 p1hA = *(const bf16x8*)(bh1 + k);
      bf16x8 p1lA = *(const bf16x8*)(bl1 + k);
      bf16x8 ahB  = *(const bf16x8*)(aph + k + 32);
      bf16x8 alB  = *(const bf16x8*)(apl + k + 32);
      bf16x8 p0hB = *(const bf16x8*)(bh0 + k + 32);
      bf16x8 p0lB = *(const bf16x8*)(bl0 + k + 32);
      bf16x8 p1hB = *(const bf16x8*)(bh1 + k + 32);
      bf16x8 p1lB = *(const bf16x8*)(bl1 + k + 32);
      acc0 = __builtin_amdgcn_mfma_f32_16x16x32_bf16(ahA, p0hA, acc0, 0, 0, 0);
      acc1 = __builtin_amdgcn_mfma_f32_16x16x32_bf16(ahA, p1hA, acc1, 0, 0, 0);
      acc0 = __builtin_amdgcn_mfma_f32_16x16x32_bf16(ahA, p0lA, acc0, 0, 0, 0);
      acc1 = __builtin_amdgcn_mfma_f32_16x16x32_bf16(ahA, p1lA, acc1, 0, 0, 0);
      acc0 = __builtin_amdgcn_mfma_f32_16x16x32_bf16(alA, p0hA, acc0, 0, 0, 0);
      acc1 = __builtin_amdgcn_mfma_f32_16x16x32_bf16(alA, p1hA, acc1, 0, 0, 0);
      acc0 = __builtin_amdgcn_mfma_f32_16x16x32_bf16(ahB, p0hB, acc0, 0, 0, 0);
      acc1 = __builtin_amdgcn_mfma_f32_16x16x32_bf16(ahB, p1hB, acc1, 0, 0, 0);
      acc0 = __builtin_amdgcn_mfma_f32_16x16x32_bf16(ahB, p0lB, acc0, 0, 0, 0);
      acc1 = __builtin_amdgcn_mfma_f32_16x16x32_bf16(ahB, p1lB, acc1, 0, 0, 0);
      acc0 = __builtin_amdgcn_mfma_f32_16x16x32_bf16(alB, p0hB, acc0, 0, 0, 0);
      acc1 = __builtin_amdgcn_mfma_f32_16x16x32_bf16(alB, p1hB, acc1, 0, 0, 0);
    }
  }

  // K-half + strip exchange. Slots: (sp0,kh1)->0,1  (sp1,kh0)->2,3  (sp1,kh1)->4,5
  __shared__ float xch[6][2][16][17];
  if (sp | kh) {
    const int ws = (sp * 2 + kh) * 2 - 2;
    #pragma unroll
    for (int r = 0; r < 4; ++r) {
      xch[ws][mb][lk * 4 + r][l16]     = acc0[r];
      xch[ws + 1][mb][lk * 4 + r][l16] = acc1[r];
    }
  }
  __syncthreads();
  if (sp == 0 && kh == 0) {
    const int hcol = hcb + l16;
    const float bi = J.bias[hcol];
    const float bf = J.bias[512 + hcol];
    const float bg = J.bias[1024 + hcol];
    const float bo = J.bias[1536 + hcol];
    #pragma unroll
    for (int r = 0; r < 4; ++r) {
      const int rr = lk * 4 + r;
      const int row = mt * 32 + mb * 16 + rr;
      const size_t idx = (size_t)row * 512 + hcol;
      float gi = acc0[r] + xch[0][mb][rr][l16] + bi;
      float gf = acc1[r] + xch[1][mb][rr][l16] + bf;
      float gg = xch[2][mb][rr][l16] + xch[4][mb][rr][l16] + bg;
      float go = xch[3][mb][rr][l16] + xch[5][mb][rr][l16] + bo;
      float si = 1.f / (1.f + expf(-gi));
      float sf = 1.f / (1.f + expf(-gf));
      float so = 1.f / (1.f + expf(-go));
      float cn = sf * J.c[idx] + si * tanhf(gg);
      float hn = so * tanhf(cn);
      J.c[idx] = cn;                      // block-private: normal store
      u16 hh = f2bf(hn);
      coh_store_u16(J.Hh + idx, (unsigned)hh);
      coh_store_u16(J.Hl + idx, (unsigned)(u16)f2bf(hn - bf2f(hh)));
    }
    vmdrain();   // h at coherence point before the counter add
  }
}

// fc for 32 rows per block (8 blocks cover B=256); 512 threads
__device__ __forceinline__ void fc_block(const u16* Hh, const u16* Hl,
                                         const float* fcW, const float* fcb,
                                         float* dout, int step, int b2) {
  int tid = threadIdx.x;
  int r = b2 * 32 + (tid >> 4);
  int cc = tid & 15;
  float s = 0.f;
  int k0 = cc * 32;
  for (int k = k0; k < k0 + 32; ++k) {
    float h = bf2f(Hh[(size_t)r * 512 + k]) + bf2f(Hl[(size_t)r * 512 + k]);
    s += h * fcW[k];
  }
  for (int off = 8; off; off >>= 1) s += __shfl_down(s, off, 16);
  if (cc == 0) dout[(size_t)r * HOR_ + step] = s + fcb[0];
}

// ---------------- dataflow sync primitives (no fences, no barriers) ----------------
struct WaitC { unsigned* p; unsigned t; };

__device__ __forceinline__ bool block_wait(const WaitC* w, int n) {
  __shared__ int okk;
  __syncthreads();                 // also protects xch reuse across phases
  if (threadIdx.x == 0) {
    int ok = 1;
    for (int i = 0; i < n && ok; ++i) {
      long spins = 0;
      while (coh_load_u32(w[i].p) < w[i].t) {   // L2-bypass: always fresh
        __builtin_amdgcn_s_sleep(1);
        if (++spins > 400000) { ok = 0; break; }   // bounded: bail, don't hang
      }
    }
    okk = ok;
  }
  __syncthreads();
  asm volatile("" ::: "memory");   // keep data loads after the spin
  return okk != 0;
}

__device__ __forceinline__ void post(unsigned* cnt) {
  __syncthreads();                 // all waves' coherent stores drained (vmdrain per wave)
  if (threadIdx.x == 0)
    __hip_atomic_fetch_add(cnt, 1u, __ATOMIC_RELAXED, __HIP_MEMORY_SCOPE_AGENT);
}

// ---------------- persistent dataflow mega kernel ----------------
struct MegaParams {
  const u16 *xh, *xl;
  const u16 *eW0h, *eW0l, *eU0h, *eU0l, *eW1h, *eW1l, *eU1h, *eU1l;
  const u16 *dU0h, *dU0l, *dW1h, *dW1l, *dU1h, *dU1l, *Whh, *Whl;
  const float *eb0, *eb1, *db0, *db1, *b0p, *fcW, *fcb;
  u16 *h0h, *h0l, *h1h, *h1l;     // slot arrays: R slots of NHH u16 each
  float *c0, *c1, *dout;
  unsigned *cnt0, *cnt1;          // per-mt monotone production counters (x32 pad)
  int R;
};

__global__ __launch_bounds__(512, 4) void mega_kernel(MegaParams P) {
  const int bid = blockIdx.x;
  const int R = P.R;

  if (bid < 256) {
    // ---------------- L0 chain ----------------
    const int bx = bid, mt = bx >> 5;
    unsigned* myc = P.cnt0 + mt * CPAD;
    unsigned* oth = P.cnt1 + mt * CPAD;
    // encoder L0: phase t produces h0 epoch t+1
    for (int t = 0; t < T_; ++t) {
      WaitC w[2]; int n = 0;
      if (t >= 1)       w[n++] = {myc, 32u * t};              // A2 = h0 epoch t
      if (t + 1 >= R)   w[n++] = {oth, 32u * (t + 1 - R)};    // ring WAR vs L1 readers
      if (!block_wait(w, n)) return;
      Job J;
      J.A1h = P.xh + (size_t)t * IN_; J.A1l = P.xl + (size_t)t * IN_;
      J.a1Stride = T_ * IN_; J.K1 = IN_;
      J.W1h = P.eW0h; J.W1l = P.eW0l;
      J.A2h = P.h0h + (size_t)(t % R) * NHH; J.A2l = P.h0l + (size_t)(t % R) * NHH;
      J.W2h = P.eU0h; J.W2l = P.eU0l; J.bias = P.eb0; J.c = P.c0;
      J.Hh = P.h0h + (size_t)((t + 1) % R) * NHH; J.Hl = P.h0l + (size_t)((t + 1) % R) * NHH;
      run_job(J, bx);
      post(myc);
    }
    // decoder L0 (fc folded via What): step s produces h0 epoch T+s+1
    for (int s = 0; s < HOR_; ++s) {
      const int e = T_ + s + 1;
      WaitC w[3]; int n = 0;
      w[n++] = {myc, 32u * (T_ + s)};                          // A2 = h0 epoch T+s
      if (s >= 1)              w[n++] = {oth, 32u * (T_ + s)}; // A1 = h1 epoch T+s
      else if (e >= R)         w[n++] = {oth, 32u * (e - R)};  // ring WAR (s=0 only)
      if (!block_wait(w, n)) return;
      Job J;
      J.A1h = P.h1h + (size_t)((T_ + s) % R) * NHH; J.A1l = P.h1l + (size_t)((T_ + s) % R) * NHH;
      J.a1Stride = 512; J.K1 = (s == 0 ? 0 : 512);
      J.W1h = P.Whh; J.W1l = P.Whl;
      J.A2h = P.h0h + (size_t)((T_ + s) % R) * NHH; J.A2l = P.h0l + (size_t)((T_ + s) % R) * NHH;
      J.W2h = P.dU0h; J.W2l = P.dU0l;
      J.bias = (s == 0 ? P.db0 : P.b0p); J.c = P.c0;
      J.Hh = P.h0h + (size_t)(e % R) * NHH; J.Hl = P.h0l + (size_t)(e % R) * NHH;
      run_job(J, bx);
      post(myc);
    }
  } else {
    // ---------------- L1 chain (+ fc piggyback on bx<8) ----------------
    const int bx = bid - 256, mt = bx >> 5;
    unsigned* myc = P.cnt1 + mt * CPAD;
    unsigned* oth = P.cnt0 + mt * CPAD;
    // encoder L1: phase t (1..T) produces h1 epoch t
    for (int t = 1; t <= T_; ++t) {
      WaitC w[2]; int n = 0;
      w[n++] = {oth, 32u * t};                                 // A1 = h0 epoch t
      if (t >= 2) w[n++] = {myc, 32u * (t - 1)};               // A2 = h1 epoch t-1
      if (!block_wait(w, n)) return;
      Job J;
      J.A1h = P.h0h + (size_t)(t % R) * NHH; J.A1l = P.h0l + (size_t)(t % R) * NHH;
      J.a1Stride = 512; J.K1 = 512;
      J.W1h = P.eW1h; J.W1l = P.eW1l;
      J.A2h = P.h1h + (size_t)((t - 1) % R) * NHH; J.A2l = P.h1l + (size_t)((t - 1) % R) * NHH;
      J.W2h = P.eU1h; J.W2l = P.eU1l; J.bias = P.eb1; J.c = P.c1;
      J.Hh = P.h1h + (size_t)(t % R) * NHH; J.Hl = P.h1l + (size_t)(t % R) * NHH;
      run_job(J, bx);
      post(myc);
    }
    // decoder L1: step s produces h1 epoch T+s+1; fc(s-1) first on bx<8
    for (int s = 0; s < HOR_; ++s) {
      if (bx < 8 && s >= 1) {
        WaitC w = {P.cnt1 + bx * CPAD, 32u * (T_ + s)};        // h1 epoch T+s rows of mt-tile bx
        if (!block_wait(&w, 1)) return;
        fc_block(P.h1h + (size_t)((T_ + s) % R) * NHH, P.h1l + (size_t)((T_ + s) % R) * NHH,
                 P.fcW, P.fcb, P.dout, s - 1, bx);
      }
      const int e = T_ + s + 1;
      WaitC w[3]; int n = 0;
      w[n++] = {oth, 32u * (T_ + s + 1)};                      // A1 = h0 epoch T+s+1
      w[n++] = {myc, 32u * (T_ + s)};                          // A2 = h1 epoch T+s
      if (e >= R && e - R > T_) w[n++] = {P.cnt1, 32u * (e - R + 1)};  // ring WAR vs fc readers
      if (!block_wait(w, n)) return;
      Job J;
      J.A1h = P.h0h + (size_t)(e % R) * NHH; J.A1l = P.h0l + (size_t)(e % R) * NHH;
      J.a1Stride = 512; J.K1 = 512;
      J.W1h = P.dW1h; J.W1l = P.dW1l;
      J.A2h = P.h1h + (size_t)((T_ + s) % R) * NHH; J.A2l = P.h1l + (size_t)((T_ + s) % R) * NHH;
      J.W2h = P.dU1h; J.W2l = P.dU1l; J.bias = P.db1; J.c = P.c1;
      J.Hh = P.h1h + (size_t)(e % R) * NHH; J.Hl = P.h1l + (size_t)(e % R) * NHH;
      run_job(J, bx);
      post(myc);
    }
    if (bx < 8) {
      WaitC w = {P.cnt1 + bx * CPAD, 32u * (T_ + HOR_)};
      if (!block_wait(&w, 1)) return;
      fc_block(P.h1h + (size_t)((T_ + HOR_) % R) * NHH, P.h1l + (size_t)((T_ + HOR_) % R) * NHH,
               P.fcW, P.fcb, P.dout, HOR_ - 1, bx);
    }
  }
}

// ---------------- host ----------------
extern "C" void kernel_launch(void* const* d_in, const int* in_sizes, int n_in,
                              void* d_out, int out_size, void* d_ws, size_t ws_size,
                              hipStream_t stream) {
  const float* x   = (const float*)d_in[0];
  const float* eW0 = (const float*)d_in[2];
  const float* eU0 = (const float*)d_in[3];
  const float* eb0 = (const float*)d_in[4];
  const float* eW1 = (const float*)d_in[5];
  const float* eU1 = (const float*)d_in[6];
  const float* eb1 = (const float*)d_in[7];
  const float* dW0 = (const float*)d_in[8];
  const float* dU0 = (const float*)d_in[9];
  const float* db0 = (const float*)d_in[10];
  const float* dW1 = (const float*)d_in[11];
  const float* dU1 = (const float*)d_in[12];
  const float* db1 = (const float*)d_in[13];
  const float* fcW = (const float*)d_in[14];
  const float* fcb = (const float*)d_in[15];
  float* dout = (float*)d_out;

  char* base = (char*)d_ws;
  size_t off = 0;
  auto alloc = [&](size_t bytes) -> char* {
    char* p = base + off;
    off = (off + bytes + 255) & ~(size_t)255;
    return p;
  };

  const size_t nx  = (size_t)B_ * T_ * IN_;
  const size_t nW0 = (size_t)G_ * IN_;
  const size_t nWH = (size_t)G_ * H_;
  u16* xhi = (u16*)alloc(nx * 2);
  u16* xlo = (u16*)alloc(nx * 2);
  u16 *eW0h = (u16*)alloc(nW0 * 2), *eW0l = (u16*)alloc(nW0 * 2);
  u16 *eU0h = (u16*)alloc(nWH * 2), *eU0l = (u16*)alloc(nWH * 2);
  u16 *eW1h = (u16*)alloc(nWH * 2), *eW1l = (u16*)alloc(nWH * 2);
  u16 *eU1h = (u16*)alloc(nWH * 2), *eU1l = (u16*)alloc(nWH * 2);
  u16 *dU0h = (u16*)alloc(nWH * 2), *dU0l = (u16*)alloc(nWH * 2);
  u16 *dW1h = (u16*)alloc(nWH * 2), *dW1l = (u16*)alloc(nWH * 2);
  u16 *dU1h = (u16*)alloc(nWH * 2), *dU1l = (u16*)alloc(nWH * 2);
  u16 *Whh  = (u16*)alloc(nWH * 2), *Whl  = (u16*)alloc(nWH * 2);
  float* b0p = (float*)alloc(G_ * 4);

  // zero-initialized region: c0, c1, counters
  char* zbase = base + off;
  float* c0 = (float*)alloc((size_t)NHH * 4);
  float* c1 = (float*)alloc((size_t)NHH * 4);
  unsigned* cnt0 = (unsigned*)alloc(8 * CPAD * 4);
  unsigned* cnt1 = (unsigned*)alloc(8 * CPAD * 4);
  size_t zbytes = (size_t)((base + off) - zbase);

  // epoch-strided h slot arrays: R slots each (full stride if ws allows)
  size_t perR = (size_t)NHH * 2 * 4;          // 4 arrays x NHH u16 = 1 MiB per slot
  size_t availR = (ws_size > off + perR * 2) ? (ws_size - off) / perR : 2;
  int R = (int)(availR < (size_t)EPOCHS ? availR : (size_t)EPOCHS);
  if (R < 2) R = 2;
  u16* h0h = (u16*)alloc((size_t)R * NHH * 2);
  u16* h0l = (u16*)alloc((size_t)R * NHH * 2);
  u16* h1h = (u16*)alloc((size_t)R * NHH * 2);
  u16* h1l = (u16*)alloc((size_t)R * NHH * 2);
  (void)in_sizes; (void)n_in; (void)out_size;

  hipMemsetAsync(zbase, 0, zbytes, stream);
  hipMemsetAsync(h0h, 0, (size_t)NHH * 2, stream);   // slot 0 = h0 epoch 0 = zeros
  hipMemsetAsync(h0l, 0, (size_t)NHH * 2, stream);
  hipMemsetAsync(h1h, 0, (size_t)NHH * 2, stream);
  hipMemsetAsync(h1l, 0, (size_t)NHH * 2, stream);

  auto split = [&](const float* s, u16* h, u16* l, size_t n) {
    int n4 = (int)(n / 4);
    split_kernel<<<dim3((n4 + 255) / 256), dim3(256), 0, stream>>>(s, h, l, n4);
  };
  split(x, xhi, xlo, nx);
  split(eW0, eW0h, eW0l, nW0);
  split(eU0, eU0h, eU0l, nWH);
  split(eW1, eW1h, eW1l, nWH);
  split(eU1, eU1h, eU1l, nWH);
  split(dU0, dU0h, dU0l, nWH);
  split(dW1, dW1h, dW1l, nWH);
  split(dU1, dU1h, dU1l, nWH);
  outer_kernel<<<dim3((int)(nWH / 256)), dim3(256), 0, stream>>>(dW0, fcW, Whh, Whl);
  bias_kernel<<<dim3((G_ + 255) / 256), dim3(256), 0, stream>>>(db0, dW0, fcb, b0p);

  MegaParams P;
  P.xh = xhi; P.xl = xlo;
  P.eW0h = eW0h; P.eW0l = eW0l; P.eU0h = eU0h; P.eU0l = eU0l;
  P.eW1h = eW1h; P.eW1l = eW1l; P.eU1h = eU1h; P.eU1l = eU1l;
  P.dU0h = dU0h; P.dU0l = dU0l; P.dW1h = dW1h; P.dW1l = dW1l;
  P.dU1h = dU1h; P.dU1l = dU1l; P.Whh = Whh; P.Whl = Whl;
  P.eb0 = eb0; P.eb1 = eb1; P.db0 = db0; P.db1 = db1; P.b0p = b0p;
  P.fcW = fcW; P.fcb = fcb;
  P.h0h = h0h; P.h0l = h0l; P.h1h = h1h; P.h1l = h1l;
  P.c0 = c0; P.c1 = c1; P.dout = dout;
  P.cnt0 = cnt0; P.cnt1 = cnt1; P.R = R;

  mega_kernel<<<dim3(512), dim3(512), 0, stream>>>(P);
}